// Round 4
// baseline (679.702 us; speedup 1.0000x reference)
//
#include <hip/hip_runtime.h>
#include <float.h>
#include <math.h>

// CrossAtt, fp16 hi/lo split MFMA, fused 2-pass flash-style attention.
// proj    : Qh/Ql, Kh/Kl (row-major f16) + Vt hi/lo (transposed) in ws.
// maskpack: valid int32 -> bitmask (1 bit per (q,k)), 4 MB.   [grid fixed!]
// fused   : pass1 QK^T (3-term f16 MFMA) -> m,z ; cross-wave reduce;
//           pass2 identical QK^T -> w=exp(S-m)*zi -> att_w (direct write)
//           -> PV (2-term: w_f16 x V hi/lo) -> cross-wave reduce -> result.

#define BB 8
#define LQ 2048
#define LK 2048
#define DD 128
#define NROWS (BB*LQ)
#define QT 16

typedef __attribute__((ext_vector_type(8))) _Float16 half8;
typedef __attribute__((ext_vector_type(4))) float f32x4;

// ws byte offsets
#define QH_OFF  (0u)
#define QL_OFF  (1u*NROWS*DD*2u)
#define KH_OFF  (2u*NROWS*DD*2u)
#define KL_OFF  (3u*NROWS*DD*2u)
#define VTH_OFF (4u*NROWS*DD*2u)
#define VTL_OFF (5u*NROWS*DD*2u)
#define BM_OFF  (6u*NROWS*DD*2u)   // bitmask: NROWS*LK/8 = 4 MB

__device__ __forceinline__ f32x4 mfma16(half8 a, half8 b, f32x4 c) {
  return __builtin_amdgcn_mfma_f32_16x16x32_f16(a, b, c, 0, 0, 0);
}

// ---------------- proj: out = src @ W^T, f16 hi/lo; V transposed ------------
__global__ __launch_bounds__(256) void proj_kernel(
    const float* __restrict__ query, const float* __restrict__ x,
    const float* __restrict__ Wq, const float* __restrict__ Wk,
    const float* __restrict__ Wv, unsigned char* __restrict__ wsb)
{
  __shared__ _Float16 TH[DD][68];
  __shared__ _Float16 TL[DD][68];
  const int which = blockIdx.y;
  const float* __restrict__ src = (which == 0) ? query : x;
  const float* __restrict__ W   = (which == 0) ? Wq : (which == 1 ? Wk : Wv);
  const int t = threadIdx.x, l = t & 63, wv = t >> 6;
  const int lr = l & 15, lg = l >> 4;
  const int r0 = blockIdx.x * 64;
  const int row = r0 + wv * 16 + lr;

  half8 ah[4], al[4];
#pragma unroll
  for (int dc = 0; dc < 4; ++dc) {
    const float* p = src + (size_t)row * DD + dc * 32 + lg * 8;
    float4 f0 = *(const float4*)p;
    float4 f1 = *(const float4*)(p + 4);
    float f[8] = {f0.x, f0.y, f0.z, f0.w, f1.x, f1.y, f1.z, f1.w};
#pragma unroll
    for (int e = 0; e < 8; ++e) {
      _Float16 h = (_Float16)f[e];
      ah[dc][e] = h;
      al[dc][e] = (_Float16)(f[e] - (float)h);
    }
  }

  f32x4 acc[8];
#pragma unroll
  for (int a = 0; a < 8; ++a) acc[a] = (f32x4){0.f, 0.f, 0.f, 0.f};

#pragma unroll
  for (int dc = 0; dc < 4; ++dc) {
#pragma unroll
    for (int a = 0; a < 8; ++a) {
      const float* p = W + (size_t)(a * 16 + lr) * DD + dc * 32 + lg * 8;
      float4 f0 = *(const float4*)p;
      float4 f1 = *(const float4*)(p + 4);
      float f[8] = {f0.x, f0.y, f0.z, f0.w, f1.x, f1.y, f1.z, f1.w};
      half8 bh, bl;
#pragma unroll
      for (int e = 0; e < 8; ++e) {
        _Float16 h = (_Float16)f[e];
        bh[e] = h;
        bl[e] = (_Float16)(f[e] - (float)h);
      }
      acc[a] = mfma16(ah[dc], bh, acc[a]);
      acc[a] = mfma16(al[dc], bh, acc[a]);
      acc[a] = mfma16(ah[dc], bl, acc[a]);
    }
  }

  if (which < 2) {
    _Float16* Oh = (_Float16*)(wsb + (which == 0 ? QH_OFF : KH_OFF));
    _Float16* Ol = (_Float16*)(wsb + (which == 0 ? QL_OFF : KL_OFF));
#pragma unroll
    for (int a = 0; a < 8; ++a)
#pragma unroll
      for (int i = 0; i < 4; ++i) {
        const int ro = r0 + wv * 16 + lg * 4 + i;
        const int co = a * 16 + lr;
        float v = acc[a][i];
        _Float16 h = (_Float16)v;
        Oh[(size_t)ro * DD + co] = h;
        Ol[(size_t)ro * DD + co] = (_Float16)(v - (float)h);
      }
  } else {
#pragma unroll
    for (int a = 0; a < 8; ++a)
#pragma unroll
      for (int i = 0; i < 4; ++i) {
        const int rl = wv * 16 + lg * 4 + i;   // local k 0..63
        const int co = a * 16 + lr;            // d
        float v = acc[a][i];
        _Float16 h = (_Float16)v;
        TH[co][rl] = h;
        TL[co][rl] = (_Float16)(v - (float)h);
      }
    __syncthreads();
    _Float16* Vh = (_Float16*)(wsb + VTH_OFF);
    _Float16* Vl = (_Float16*)(wsb + VTL_OFF);
    const int b = r0 >> 11, kloc = r0 & 2047;
    const int d = t >> 1, half = t & 1;
    const size_t gb = ((size_t)(b * DD + d)) * LK + kloc + half * 32;
#pragma unroll
    for (int j = 0; j < 8; ++j) {
      *(ushort4*)(Vh + gb + j * 4) = *(const ushort4*)&TH[d][half * 32 + j * 4];
      *(ushort4*)(Vl + gb + j * 4) = *(const ushort4*)&TL[d][half * 32 + j * 4];
    }
  }
}

// ---------------- maskpack: valid -> 1 bit per element ----------------------
__global__ __launch_bounds__(256) void maskpack_kernel(
    const int* __restrict__ valid, unsigned long long* __restrict__ bm)
{
  const int t = threadIdx.x, l = t & 63, wv = t >> 6;
  const size_t base = (size_t)blockIdx.x * 32768 + (size_t)wv * 8192;
  for (int it = 0; it < 128; ++it) {
    int v = valid[base + (size_t)it * 64 + l];
    unsigned long long m = __ballot(v > 0);
    if (l == 0) bm[(base >> 6) + it] = m;
  }
}

// ---------------- fused attention -------------------------------------------
__global__ __launch_bounds__(256) void fused_kernel(
    const unsigned char* __restrict__ wsb,
    float* __restrict__ att, float* __restrict__ res)
{
  const int t = threadIdx.x, l = t & 63, wv = t >> 6;
  const int lr = l & 15, lg = l >> 4;
  const int qt = blockIdx.x, b = blockIdx.y;
  const int rowg = b * LQ + qt * QT;     // block's 16 q-rows
  const _Float16* Qh = (const _Float16*)(wsb + QH_OFF);
  const _Float16* Ql = (const _Float16*)(wsb + QL_OFF);
  const _Float16* Kh = (const _Float16*)(wsb + KH_OFF);
  const _Float16* Kl = (const _Float16*)(wsb + KL_OFF);
  const _Float16* Vh = (const _Float16*)(wsb + VTH_OFF);
  const _Float16* Vl = (const _Float16*)(wsb + VTL_OFF);
  const unsigned* bm = (const unsigned*)(wsb + BM_OFF);

  __shared__ float SH[4 * 16 * 132];     // Wl view: wv*1088+r*68+c ; Os view: wv*2112+r*132+d
  __shared__ float Ms[4][16], Zs[4][16], Mf[16], Zif[16];

  // Q fragments (held through both passes)
  half8 qh[4], ql[4];
#pragma unroll
  for (int dc = 0; dc < 4; ++dc) {
    const size_t idx = ((size_t)(rowg + lr)) * DD + dc * 32 + lg * 8;
    qh[dc] = *(const half8*)(Qh + idx);
    ql[dc] = *(const half8*)(Ql + idx);
  }

  const int kbase = wv * 512;

  // ---- pass 1: m,z over this wave's k-quarter ----
  float m_run[4], z_run[4];
#pragma unroll
  for (int i = 0; i < 4; ++i) { m_run[i] = -FLT_MAX; z_run[i] = 0.f; }

  for (int kt = 0; kt < 8; ++kt) {
    const int k0 = kbase + kt * 64;
    unsigned mw0[4], mw1[4];
#pragma unroll
    for (int i = 0; i < 4; ++i) {
      uint2 u = *(const uint2*)(bm + ((size_t)(rowg + lg * 4 + i)) * 64 + (k0 >> 5));
      mw0[i] = u.x; mw1[i] = u.y;
    }
    f32x4 acc[4];
#pragma unroll
    for (int kg = 0; kg < 4; ++kg) acc[kg] = (f32x4){0.f, 0.f, 0.f, 0.f};
#pragma unroll
    for (int kg = 0; kg < 4; ++kg)
#pragma unroll
      for (int dc = 0; dc < 4; ++dc) {
        const size_t kidx = ((size_t)(b * LK + k0 + kg * 16 + lr)) * DD + dc * 32 + lg * 8;
        half8 bh = *(const half8*)(Kh + kidx);
        half8 bl = *(const half8*)(Kl + kidx);
        acc[kg] = mfma16(qh[dc], bh, acc[kg]);
        acc[kg] = mfma16(ql[dc], bh, acc[kg]);
        acc[kg] = mfma16(qh[dc], bl, acc[kg]);
      }
#pragma unroll
    for (int i = 0; i < 4; ++i) {
      float sv[4];
#pragma unroll
      for (int kg = 0; kg < 4; ++kg) {
        unsigned w = (kg < 2) ? mw0[i] : mw1[i];
        int bit = (w >> (((kg & 1) * 16) + lr)) & 1;
        sv[kg] = bit ? acc[kg][i] : -INFINITY;
      }
      float tm = fmaxf(fmaxf(sv[0], sv[1]), fmaxf(sv[2], sv[3]));
#pragma unroll
      for (int o = 1; o < 16; o <<= 1) tm = fmaxf(tm, __shfl_xor(tm, o));
      const float mo = m_run[i], mn = fmaxf(mo, tm);
      float za = __expf(sv[0] - mn) + __expf(sv[1] - mn) +
                 __expf(sv[2] - mn) + __expf(sv[3] - mn);
      z_run[i] = z_run[i] * __expf(mo - mn) + za;   // lane-partial z
      m_run[i] = mn;
    }
  }
#pragma unroll
  for (int i = 0; i < 4; ++i) {
    float z = z_run[i];
#pragma unroll
    for (int o = 1; o < 16; o <<= 1) z += __shfl_xor(z, o);
    if (lr == 0) { Ms[wv][lg * 4 + i] = m_run[i]; Zs[wv][lg * 4 + i] = z; }
  }
  __syncthreads();
  if (t < 16) {
    float m0 = Ms[0][t], m1 = Ms[1][t], m2 = Ms[2][t], m3 = Ms[3][t];
    float m = fmaxf(fmaxf(m0, m1), fmaxf(m2, m3));
    float z = Zs[0][t] * __expf(m0 - m) + Zs[1][t] * __expf(m1 - m) +
              Zs[2][t] * __expf(m2 - m) + Zs[3][t] * __expf(m3 - m);
    Mf[t] = m;
    Zif[t] = (z > 0.f) ? 1.f / z : 0.f;
  }
  __syncthreads();

  // ---- pass 2: recompute S (bit-identical), write att_w, PV ----
  f32x4 oacc[8];
#pragma unroll
  for (int df = 0; df < 8; ++df) oacc[df] = (f32x4){0.f, 0.f, 0.f, 0.f};
  float* Wl = SH + wv * 1088;

  for (int kt = 0; kt < 8; ++kt) {
    const int k0 = kbase + kt * 64;
    unsigned mw0[4], mw1[4];
#pragma unroll
    for (int i = 0; i < 4; ++i) {
      uint2 u = *(const uint2*)(bm + ((size_t)(rowg + lg * 4 + i)) * 64 + (k0 >> 5));
      mw0[i] = u.x; mw1[i] = u.y;
    }
    f32x4 acc[4];
#pragma unroll
    for (int kg = 0; kg < 4; ++kg) acc[kg] = (f32x4){0.f, 0.f, 0.f, 0.f};
#pragma unroll
    for (int kg = 0; kg < 4; ++kg)
#pragma unroll
      for (int dc = 0; dc < 4; ++dc) {
        const size_t kidx = ((size_t)(b * LK + k0 + kg * 16 + lr)) * DD + dc * 32 + lg * 8;
        half8 bh = *(const half8*)(Kh + kidx);
        half8 bl = *(const half8*)(Kl + kidx);
        acc[kg] = mfma16(qh[dc], bh, acc[kg]);
        acc[kg] = mfma16(ql[dc], bh, acc[kg]);
        acc[kg] = mfma16(qh[dc], bl, acc[kg]);
      }
    // w = exp(S - m)*zi -> per-wave LDS tile (C-layout)
#pragma unroll
    for (int i = 0; i < 4; ++i) {
      const int r = lg * 4 + i;
      const float mst = Mf[r], zi = Zif[r];
#pragma unroll
      for (int kg = 0; kg < 4; ++kg) {
        unsigned w = (kg < 2) ? mw0[i] : mw1[i];
        int bit = (w >> (((kg & 1) * 16) + lr)) & 1;
        float sm = bit ? acc[kg][i] : -INFINITY;
        Wl[r * 68 + kg * 16 + lr] = __expf(sm - mst) * zi;
      }
    }
    // Compiler memory barrier: keep the cross-lane ds_writes above ordered
    // before the ds_reads below (HW DS ops are in-order per wave; this only
    // stops compiler reordering). Zero runtime cost.
    asm volatile("" ::: "memory");
    // A-frags of w (row = lr, dims k)
    half8 wh[2];
#pragma unroll
    for (int kc = 0; kc < 2; ++kc) {
      float4 a0 = *(const float4*)&Wl[lr * 68 + kc * 32 + lg * 8];
      float4 a1 = *(const float4*)&Wl[lr * 68 + kc * 32 + lg * 8 + 4];
      float f[8] = {a0.x, a0.y, a0.z, a0.w, a1.x, a1.y, a1.z, a1.w};
#pragma unroll
      for (int e = 0; e < 8; ++e) wh[kc][e] = (_Float16)f[e];
    }
    // vectorized att_w store from LDS
    {
      const int r = l >> 2, c = (l & 3) * 16;
      float* ap = att + ((size_t)(rowg + r)) * LK + k0 + c;
#pragma unroll
      for (int j = 0; j < 4; ++j)
        *(float4*)(ap + j * 4) = *(const float4*)&Wl[r * 68 + c + j * 4];
    }
    // PV: oacc[q][d] += w[q][k] * V[k][d]  (2-term: w_h x (vh + vl))
#pragma unroll
    for (int kc = 0; kc < 2; ++kc)
#pragma unroll
      for (int df = 0; df < 8; ++df) {
        const size_t vidx = ((size_t)(b * DD + df * 16 + lr)) * LK + k0 + kc * 32 + lg * 8;
        half8 vh = *(const half8*)(Vh + vidx);
        half8 vl = *(const half8*)(Vl + vidx);
        oacc[df] = mfma16(wh[kc], vh, oacc[df]);
        oacc[df] = mfma16(wh[kc], vl, oacc[df]);
      }
  }

  // ---- cross-wave PV reduce ----
  __syncthreads();                        // all Wl use done before Os overwrite
  float* Os = SH + wv * 2112;
#pragma unroll
  for (int df = 0; df < 8; ++df)
#pragma unroll
    for (int i = 0; i < 4; ++i)
      Os[(lg * 4 + i) * 132 + df * 16 + lr] = oacc[df][i];
  __syncthreads();
  {
    const int r = t >> 4, d = (t & 15) * 8;
#pragma unroll
    for (int j = 0; j < 8; j += 4) {
      float4 s0 = *(const float4*)&SH[0 * 2112 + r * 132 + d + j];
      float4 s1 = *(const float4*)&SH[1 * 2112 + r * 132 + d + j];
      float4 s2 = *(const float4*)&SH[2 * 2112 + r * 132 + d + j];
      float4 s3 = *(const float4*)&SH[3 * 2112 + r * 132 + d + j];
      float4 s;
      s.x = (s0.x + s1.x) + (s2.x + s3.x);
      s.y = (s0.y + s1.y) + (s2.y + s3.y);
      s.z = (s0.z + s1.z) + (s2.z + s3.z);
      s.w = (s0.w + s1.w) + (s2.w + s3.w);
      *(float4*)&res[((size_t)(rowg + r)) * DD + d + j] = s;
    }
  }
}

extern "C" void kernel_launch(void* const* d_in, const int* in_sizes, int n_in,
                              void* d_out, int out_size, void* d_ws, size_t ws_size,
                              hipStream_t stream)
{
  (void)in_sizes; (void)n_in; (void)out_size; (void)ws_size;
  const float* query = (const float*)d_in[0];
  const float* x     = (const float*)d_in[1];
  const int*   valid = (const int*)d_in[2];
  const float* Wq    = (const float*)d_in[3];
  const float* Wk    = (const float*)d_in[4];
  const float* Wv    = (const float*)d_in[5];

  float* out = (float*)d_out;
  float* res = out;                          // [B][LQ][D]
  float* att = out + (size_t)NROWS * DD;     // [B][LQ][LK]
  unsigned char* wsb = (unsigned char*)d_ws; // 28 MB used

  proj_kernel<<<dim3(NROWS / 64, 3), 256, 0, stream>>>(query, x, Wq, Wk, Wv, wsb);
  // FIX: (NROWS*LK)/32768 = 1024 blocks (previous expression hit integer-div 0)
  maskpack_kernel<<<dim3((NROWS / 16) * (LK / 2048)), 256, 0, stream>>>(
      valid, (unsigned long long*)(wsb + BM_OFF));
  fused_kernel<<<dim3(LQ / QT, BB), 256, 0, stream>>>(wsb, att, res);
}

// Round 5
// 428.230 us; speedup vs baseline: 1.5872x; 1.5872x over previous
//
#include <hip/hip_runtime.h>
#include <float.h>
#include <math.h>

// CrossAtt, fp16 hi/lo split MFMA, LDS-staged GEMM-structured pipeline.
// proj    : Qh/Ql,Kh/Kl (row-major f16) + Vt hi/lo (transposed) in ws. LDS-coalesced src.
// maskpack: valid int32 -> bitmask, 4 MB.
// scores  : S = QK^T (3-term f16 MFMA, K staged in LDS, T14 async-stage),
//           mask -> raw S to att, per-row m,z partials (4 k-splits).
// pv      : S read coalesced -> w=exp(S-m)*zi -> att_w + LDS w-tile,
//           PV (2-term, Vt staged in LDS) -> atomicAdd into zeroed res.

#define BB 8
#define LQ 2048
#define LK 2048
#define DD 128
#define NROWS (BB*LQ)
#define KS 4

typedef __attribute__((ext_vector_type(8))) _Float16 half8;
typedef __attribute__((ext_vector_type(8))) unsigned short ushort8;
typedef __attribute__((ext_vector_type(4))) float f32x4;

// ws byte offsets
#define QH_OFF  (0u)
#define QL_OFF  (1u*NROWS*DD*2u)
#define KH_OFF  (2u*NROWS*DD*2u)
#define KL_OFF  (3u*NROWS*DD*2u)
#define VTH_OFF (4u*NROWS*DD*2u)
#define VTL_OFF (5u*NROWS*DD*2u)
#define BM_OFF  (6u*NROWS*DD*2u)            // 4 MB bitmask
#define MZ_OFF  (BM_OFF + (unsigned)NROWS*(LK/8))  // M[4][NROWS], Z[4][NROWS] f32

__device__ __forceinline__ f32x4 mfma16(half8 a, half8 b, f32x4 c) {
  return __builtin_amdgcn_mfma_f32_16x16x32_f16(a, b, c, 0, 0, 0);
}

// ---------------- proj ------------------------------------------------------
__global__ __launch_bounds__(256, 3) void proj_kernel(
    const float* __restrict__ query, const float* __restrict__ x,
    const float* __restrict__ Wq, const float* __restrict__ Wk,
    const float* __restrict__ Wv, unsigned char* __restrict__ wsb)
{
  __shared__ float SB[8704];   // src tile [64][132]; reused as TH/TL f16 [128][68]
  const int which = blockIdx.y;
  const float* __restrict__ src = (which == 0) ? query : x;
  const float* __restrict__ W   = (which == 0) ? Wq : (which == 1 ? Wk : Wv);
  const int t = threadIdx.x, l = t & 63, wv = t >> 6;
  const int lr = l & 15, lg = l >> 4;
  const int r0 = blockIdx.x * 64;

  // coalesced stage of 64 src rows
#pragma unroll
  for (int j = 0; j < 8; ++j) {
    const int flat = j * 1024 + t * 4;
    const int row = flat >> 7, col = flat & 127;
    *(float4*)&SB[row * 132 + col] = *(const float4*)&src[(size_t)(r0 + row) * DD + col];
  }
  __syncthreads();

  half8 ah[4], al[4];
#pragma unroll
  for (int dc = 0; dc < 4; ++dc) {
    const int base = (wv * 16 + lr) * 132 + dc * 32 + lg * 8;
    float4 f0 = *(const float4*)&SB[base];
    float4 f1 = *(const float4*)&SB[base + 4];
    float f[8] = {f0.x, f0.y, f0.z, f0.w, f1.x, f1.y, f1.z, f1.w};
#pragma unroll
    for (int e = 0; e < 8; ++e) {
      _Float16 h = (_Float16)f[e];
      ah[dc][e] = h;
      al[dc][e] = (_Float16)(f[e] - (float)h);
    }
  }
  __syncthreads();   // SB reads done (SB reused below for V transpose)

  f32x4 acc[8];
#pragma unroll
  for (int a = 0; a < 8; ++a) acc[a] = (f32x4){0.f, 0.f, 0.f, 0.f};

#pragma unroll
  for (int dc = 0; dc < 4; ++dc) {
#pragma unroll
    for (int a = 0; a < 8; ++a) {
      const float* p = W + (size_t)(a * 16 + lr) * DD + dc * 32 + lg * 8;
      float4 f0 = *(const float4*)p;
      float4 f1 = *(const float4*)(p + 4);
      float f[8] = {f0.x, f0.y, f0.z, f0.w, f1.x, f1.y, f1.z, f1.w};
      half8 bh, bl;
#pragma unroll
      for (int e = 0; e < 8; ++e) {
        _Float16 h = (_Float16)f[e];
        bh[e] = h;
        bl[e] = (_Float16)(f[e] - (float)h);
      }
      acc[a] = mfma16(ah[dc], bh, acc[a]);
      acc[a] = mfma16(al[dc], bh, acc[a]);
      acc[a] = mfma16(ah[dc], bl, acc[a]);
    }
  }

  if (which < 2) {
    _Float16* Oh = (_Float16*)(wsb + (which == 0 ? QH_OFF : KH_OFF));
    _Float16* Ol = (_Float16*)(wsb + (which == 0 ? QL_OFF : KL_OFF));
#pragma unroll
    for (int a = 0; a < 8; ++a)
#pragma unroll
      for (int i = 0; i < 4; ++i) {
        const int ro = r0 + wv * 16 + lg * 4 + i;
        const int co = a * 16 + lr;
        float v = acc[a][i];
        _Float16 h = (_Float16)v;
        Oh[(size_t)ro * DD + co] = h;
        Ol[(size_t)ro * DD + co] = (_Float16)(v - (float)h);
      }
  } else {
    _Float16* TH = (_Float16*)SB;          // [128][68]
    _Float16* TL = TH + 8704;
#pragma unroll
    for (int a = 0; a < 8; ++a)
#pragma unroll
      for (int i = 0; i < 4; ++i) {
        const int rl = wv * 16 + lg * 4 + i;   // local k
        const int co = a * 16 + lr;            // d
        float v = acc[a][i];
        _Float16 h = (_Float16)v;
        TH[co * 68 + rl] = h;
        TL[co * 68 + rl] = (_Float16)(v - (float)h);
      }
    __syncthreads();
    _Float16* Vh = (_Float16*)(wsb + VTH_OFF);
    _Float16* Vl = (_Float16*)(wsb + VTL_OFF);
    const int b = r0 >> 11, kloc = r0 & 2047;
    const int d = t >> 1, hh = t & 1;
    const size_t gb = ((size_t)(b * DD + d)) * LK + kloc + hh * 32;
#pragma unroll
    for (int j = 0; j < 8; ++j) {
      *(ushort4*)(Vh + gb + j * 4) = *(const ushort4*)&TH[d * 68 + hh * 32 + j * 4];
      *(ushort4*)(Vl + gb + j * 4) = *(const ushort4*)&TL[d * 68 + hh * 32 + j * 4];
    }
  }
}

// ---------------- maskpack --------------------------------------------------
__global__ __launch_bounds__(256) void maskpack_kernel(
    const int* __restrict__ valid, unsigned long long* __restrict__ bm)
{
  const int t = threadIdx.x, l = t & 63, wv = t >> 6;
  const size_t base = (size_t)blockIdx.x * 32768 + (size_t)wv * 8192;
  for (int it = 0; it < 32; ++it) {
    int v0 = valid[base + (size_t)(it * 4 + 0) * 64 + l];
    int v1 = valid[base + (size_t)(it * 4 + 1) * 64 + l];
    int v2 = valid[base + (size_t)(it * 4 + 2) * 64 + l];
    int v3 = valid[base + (size_t)(it * 4 + 3) * 64 + l];
    unsigned long long m0 = __ballot(v0 > 0);
    unsigned long long m1 = __ballot(v1 > 0);
    unsigned long long m2 = __ballot(v2 > 0);
    unsigned long long m3 = __ballot(v3 > 0);
    if (l == 0) {
      bm[(base >> 6) + it * 4 + 0] = m0;
      bm[(base >> 6) + it * 4 + 1] = m1;
      bm[(base >> 6) + it * 4 + 2] = m2;
      bm[(base >> 6) + it * 4 + 3] = m3;
    }
  }
}

// ---------------- scores ----------------------------------------------------
// grid (LQ/64, B, KS). Block: 4 waves x 16 q-rows, k-range 512 (8 tiles of 64).
__global__ __launch_bounds__(256, 4) void scores_kernel(
    const unsigned char* __restrict__ wsb, float* __restrict__ att)
{
  __shared__ unsigned short KHs[64 * 136];
  __shared__ unsigned short KLs[64 * 136];
  const int t = threadIdx.x, l = t & 63, wv = t >> 6;
  const int lr = l & 15, lg = l >> 4;
  const int qb = blockIdx.x, b = blockIdx.y, ks = blockIdx.z;
  const int rowg = b * LQ + qb * 64;
  const int kbase = ks * 512;
  const _Float16* QH = (const _Float16*)(wsb + QH_OFF);
  const _Float16* QL = (const _Float16*)(wsb + QL_OFF);
  const _Float16* KH = (const _Float16*)(wsb + KH_OFF);
  const _Float16* KL = (const _Float16*)(wsb + KL_OFF);
  const unsigned* bm32 = (const unsigned*)(wsb + BM_OFF);
  float* M = (float*)(wsb + MZ_OFF);
  float* Z = M + KS * NROWS;

  // Q fragments (registers, whole block lifetime)
  half8 qh[4], ql[4];
#pragma unroll
  for (int dc = 0; dc < 4; ++dc) {
    const size_t idx = ((size_t)(rowg + wv * 16 + lr)) * DD + dc * 32 + lg * 8;
    qh[dc] = *(const half8*)(QH + idx);
    ql[dc] = *(const half8*)(QL + idx);
  }

  ushort8 rh[4], rl[4];
  auto issue_stage = [&](int kt) {
#pragma unroll
    for (int j = 0; j < 4; ++j) {
      const int flat = j * 2048 + t * 8;
      const int row = flat >> 7, col = flat & 127;
      const size_t g = ((size_t)(b * LK + kbase + kt * 64 + row)) * DD + col;
      rh[j] = *(const ushort8*)(KH + g);
      rl[j] = *(const ushort8*)(KL + g);
    }
  };
  auto write_stage = [&]() {
#pragma unroll
    for (int j = 0; j < 4; ++j) {
      const int flat = j * 2048 + t * 8;
      const int row = flat >> 7, col = flat & 127;
      *(ushort8*)&KHs[row * 136 + col] = rh[j];
      *(ushort8*)&KLs[row * 136 + col] = rl[j];
    }
  };

  issue_stage(0);
  write_stage();

  float m_run[4], z_run[4];
#pragma unroll
  for (int i = 0; i < 4; ++i) { m_run[i] = -FLT_MAX; z_run[i] = 0.f; }

  for (int kt = 0; kt < 8; ++kt) {
    const int k0 = kbase + kt * 64;
    if (kt < 7) issue_stage(kt + 1);
    unsigned mw0[4], mw1[4];
#pragma unroll
    for (int i = 0; i < 4; ++i) {
      uint2 u = *(const uint2*)(bm32 + ((size_t)(rowg + wv * 16 + lg * 4 + i)) * 64 + (k0 >> 5));
      mw0[i] = u.x; mw1[i] = u.y;
    }
    __syncthreads();   // tile kt staged

    f32x4 acc[4];
#pragma unroll
    for (int kg = 0; kg < 4; ++kg) acc[kg] = (f32x4){0.f, 0.f, 0.f, 0.f};
#pragma unroll
    for (int kg = 0; kg < 4; ++kg)
#pragma unroll
      for (int dc = 0; dc < 4; ++dc) {
        half8 bh = *(const half8*)&KHs[(kg * 16 + lr) * 136 + dc * 32 + lg * 8];
        half8 bl = *(const half8*)&KLs[(kg * 16 + lr) * 136 + dc * 32 + lg * 8];
        acc[kg] = mfma16(qh[dc], bh, acc[kg]);
        acc[kg] = mfma16(ql[dc], bh, acc[kg]);
        acc[kg] = mfma16(qh[dc], bl, acc[kg]);
      }

#pragma unroll
    for (int i = 0; i < 4; ++i) {
      float sv[4];
      float* ap = att + ((size_t)(rowg + wv * 16 + lg * 4 + i)) * LK + k0 + lr;
#pragma unroll
      for (int kg = 0; kg < 4; ++kg) {
        unsigned w = (kg < 2) ? mw0[i] : mw1[i];
        int bit = (w >> (((kg & 1) * 16) + lr)) & 1;
        float v = bit ? acc[kg][i] : -INFINITY;
        sv[kg] = v;
        ap[kg * 16] = v;
      }
      float tm = fmaxf(fmaxf(sv[0], sv[1]), fmaxf(sv[2], sv[3]));
#pragma unroll
      for (int o = 1; o < 16; o <<= 1) tm = fmaxf(tm, __shfl_xor(tm, o));
      const float mo = m_run[i], mn = fmaxf(mo, tm);
      float za = __expf(sv[0] - mn) + __expf(sv[1] - mn) +
                 __expf(sv[2] - mn) + __expf(sv[3] - mn);
      z_run[i] = z_run[i] * __expf(mo - mn) + za;
      m_run[i] = mn;
    }
    __syncthreads();   // LDS reads done
    if (kt < 7) write_stage();
  }

#pragma unroll
  for (int i = 0; i < 4; ++i) {
    float z = z_run[i];
#pragma unroll
    for (int o = 1; o < 16; o <<= 1) z += __shfl_xor(z, o);
    if (lr == 0) {
      const size_t row = (size_t)(rowg + wv * 16 + lg * 4 + i);
      M[(size_t)ks * NROWS + row] = m_run[i];
      Z[(size_t)ks * NROWS + row] = z;
    }
  }
}

// ---------------- pv --------------------------------------------------------
// grid (LQ/64, B, KS). Block: 4 waves x 16 q-rows, k-range 512.
__global__ __launch_bounds__(256, 3) void pv_kernel(
    const unsigned char* __restrict__ wsb, float* __restrict__ att,
    float* __restrict__ res)
{
  __shared__ float Ws[64 * 68];             // w tile [64][68] f32
  __shared__ unsigned short VHs[128 * 72];  // Vt hi [128][72]
  __shared__ unsigned short VLs[128 * 72];
  const int t = threadIdx.x, l = t & 63, wv = t >> 6;
  const int lr = l & 15, lg = l >> 4;
  const int qb = blockIdx.x, b = blockIdx.y, kp = blockIdx.z;
  const int rowg = b * LQ + qb * 64;
  const int kbase = kp * 512;
  const _Float16* VTH = (const _Float16*)(wsb + VTH_OFF);
  const _Float16* VTL = (const _Float16*)(wsb + VTL_OFF);
  const float* M = (const float*)(wsb + MZ_OFF);
  const float* Z = M + KS * NROWS;

  // per-thread staging row & global m,zi for it
  const int srow = t >> 2, scb = (t & 3) * 16;
  float mg, zi;
  {
    const size_t row = (size_t)(rowg + srow);
    float m0 = M[row], m1 = M[NROWS + row], m2 = M[2 * NROWS + row], m3 = M[3 * NROWS + row];
    mg = fmaxf(fmaxf(m0, m1), fmaxf(m2, m3));
    float z = Z[row] * __expf(m0 - mg) + Z[NROWS + row] * __expf(m1 - mg) +
              Z[2 * NROWS + row] * __expf(m2 - mg) + Z[3 * NROWS + row] * __expf(m3 - mg);
    zi = (z > 0.f) ? 1.f / z : 0.f;
  }

  ushort8 vhr[4], vlr[4];
  float4 sr[4];
  auto issue_V = [&](int kt) {
#pragma unroll
    for (int j = 0; j < 4; ++j) {
      const int flat = j * 2048 + t * 8;
      const int d = flat >> 6, kk = flat & 63;
      const size_t g = ((size_t)(b * DD + d)) * LK + kbase + kt * 64 + kk;
      vhr[j] = *(const ushort8*)(VTH + g);
      vlr[j] = *(const ushort8*)(VTL + g);
    }
  };
  auto issue_S = [&](int kt) {
    const size_t rb = (size_t)(rowg + srow) * LK + kbase + kt * 64 + scb;
#pragma unroll
    for (int j = 0; j < 4; ++j) sr[j] = *(const float4*)&att[rb + j * 4];
  };
  auto wcompute_write = [&](int kt) {
    const size_t rb = (size_t)(rowg + srow) * LK + kbase + kt * 64 + scb;
#pragma unroll
    for (int j = 0; j < 4; ++j) {
      float4 w4;
      w4.x = __expf(sr[j].x - mg) * zi;
      w4.y = __expf(sr[j].y - mg) * zi;
      w4.z = __expf(sr[j].z - mg) * zi;
      w4.w = __expf(sr[j].w - mg) * zi;
      *(float4*)&Ws[srow * 68 + scb + j * 4] = w4;
      *(float4*)&att[rb + j * 4] = w4;
    }
#pragma unroll
    for (int j = 0; j < 4; ++j) {
      const int flat = j * 2048 + t * 8;
      const int d = flat >> 6, kk = flat & 63;
      *(ushort8*)&VHs[d * 72 + kk] = vhr[j];
      *(ushort8*)&VLs[d * 72 + kk] = vlr[j];
    }
  };

  f32x4 oacc[8];
#pragma unroll
  for (int df = 0; df < 8; ++df) oacc[df] = (f32x4){0.f, 0.f, 0.f, 0.f};

  issue_V(0); issue_S(0);
  wcompute_write(0);

  for (int kt = 0; kt < 8; ++kt) {
    if (kt < 7) { issue_V(kt + 1); issue_S(kt + 1); }
    __syncthreads();   // tiles kt visible

#pragma unroll
    for (int kc = 0; kc < 2; ++kc) {
      const int abase = (wv * 16 + lr) * 68 + kc * 32 + lg * 8;
      float4 a0 = *(const float4*)&Ws[abase];
      float4 a1 = *(const float4*)&Ws[abase + 4];
      half8 wf;
      wf[0] = (_Float16)a0.x; wf[1] = (_Float16)a0.y;
      wf[2] = (_Float16)a0.z; wf[3] = (_Float16)a0.w;
      wf[4] = (_Float16)a1.x; wf[5] = (_Float16)a1.y;
      wf[6] = (_Float16)a1.z; wf[7] = (_Float16)a1.w;
#pragma unroll
      for (int df = 0; df < 8; ++df) {
        half8 vh = *(const half8*)&VHs[(df * 16 + lr) * 72 + kc * 32 + lg * 8];
        half8 vl = *(const half8*)&VLs[(df * 16 + lr) * 72 + kc * 32 + lg * 8];
        oacc[df] = mfma16(wf, vh, oacc[df]);
        oacc[df] = mfma16(wf, vl, oacc[df]);
      }
    }
    __syncthreads();   // LDS reads done
    if (kt < 7) wcompute_write(kt + 1);
  }

#pragma unroll
  for (int df = 0; df < 8; ++df)
#pragma unroll
    for (int i = 0; i < 4; ++i)
      atomicAdd(&res[((size_t)(rowg + wv * 16 + lg * 4 + i)) * DD + df * 16 + lr],
                oacc[df][i]);
}

extern "C" void kernel_launch(void* const* d_in, const int* in_sizes, int n_in,
                              void* d_out, int out_size, void* d_ws, size_t ws_size,
                              hipStream_t stream)
{
  (void)in_sizes; (void)n_in; (void)out_size; (void)ws_size;
  const float* query = (const float*)d_in[0];
  const float* x     = (const float*)d_in[1];
  const int*   valid = (const int*)d_in[2];
  const float* Wq    = (const float*)d_in[3];
  const float* Wk    = (const float*)d_in[4];
  const float* Wv    = (const float*)d_in[5];

  float* out = (float*)d_out;
  float* res = out;                          // [B][LQ][D]
  float* att = out + (size_t)NROWS * DD;     // [B][LQ][LK]
  unsigned char* wsb = (unsigned char*)d_ws; // ~30 MB used

  hipMemsetAsync(res, 0, (size_t)NROWS * DD * sizeof(float), stream);
  proj_kernel<<<dim3(NROWS / 64, 3), 256, 0, stream>>>(query, x, Wq, Wk, Wv, wsb);
  maskpack_kernel<<<dim3(1024), 256, 0, stream>>>(
      valid, (unsigned long long*)(wsb + BM_OFF));
  scores_kernel<<<dim3(LQ / 64, BB, KS), 256, 0, stream>>>(wsb, att);
  pv_kernel<<<dim3(LQ / 64, BB, KS), 256, 0, stream>>>(wsb, att, res);
}

// Round 6
// 416.744 us; speedup vs baseline: 1.6310x; 1.0276x over previous
//
#include <hip/hip_runtime.h>
#include <float.h>
#include <math.h>

// CrossAtt, fp16 split MFMA, XOR-swizzled LDS staging, conflict-free by design.
// proj    : Qh/Ql,Kh/Kl (row-major f16) + Vt hi (transposed f16) in ws.
// maskpack: valid int32 -> bitmask, 4 MB.
// scores  : S = QK^T (3-term f16 MFMA, K hi/lo staged in swizzled LDS),
//           mask -> raw S to att, per-row m,z partials (4 k-splits).
// pv      : S read coalesced -> w=exp(S-m)*zi -> att_w + swizzled f16 w-tile,
//           PV (1-term w*Vh, Vt staged swizzled) -> atomicAdd into zeroed res.

#define BB 8
#define LQ 2048
#define LK 2048
#define DD 128
#define NROWS (BB*LQ)
#define KS 4

typedef __attribute__((ext_vector_type(8))) _Float16 half8;
typedef __attribute__((ext_vector_type(4))) float f32x4;

// ws byte offsets
#define QH_OFF  (0u)
#define QL_OFF  (1u*NROWS*DD*2u)
#define KH_OFF  (2u*NROWS*DD*2u)
#define KL_OFF  (3u*NROWS*DD*2u)
#define VTH_OFF (4u*NROWS*DD*2u)
#define VTL_OFF (5u*NROWS*DD*2u)   // unused by pv now (kept: proj still writes it)
#define BM_OFF  (6u*NROWS*DD*2u)            // 4 MB bitmask
#define MZ_OFF  (BM_OFF + (unsigned)NROWS*(LK/8))  // M[4][NROWS], Z[4][NROWS] f32

__device__ __forceinline__ f32x4 mfma16(half8 a, half8 b, f32x4 c) {
  return __builtin_amdgcn_mfma_f32_16x16x32_f16(a, b, c, 0, 0, 0);
}

// ---------------- proj ------------------------------------------------------
__global__ __launch_bounds__(256, 3) void proj_kernel(
    const float* __restrict__ query, const float* __restrict__ x,
    const float* __restrict__ Wq, const float* __restrict__ Wk,
    const float* __restrict__ Wv, unsigned char* __restrict__ wsb)
{
  __shared__ float SB[8704];   // src tile [64][132]; reused as TH/TL f16 [128][68]
  const int which = blockIdx.y;
  const float* __restrict__ src = (which == 0) ? query : x;
  const float* __restrict__ W   = (which == 0) ? Wq : (which == 1 ? Wk : Wv);
  const int t = threadIdx.x, l = t & 63, wv = t >> 6;
  const int lr = l & 15, lg = l >> 4;
  const int r0 = blockIdx.x * 64;

#pragma unroll
  for (int j = 0; j < 8; ++j) {
    const int flat = j * 1024 + t * 4;
    const int row = flat >> 7, col = flat & 127;
    *(float4*)&SB[row * 132 + col] = *(const float4*)&src[(size_t)(r0 + row) * DD + col];
  }
  __syncthreads();

  half8 ah[4], al[4];
#pragma unroll
  for (int dc = 0; dc < 4; ++dc) {
    const int base = (wv * 16 + lr) * 132 + dc * 32 + lg * 8;
    float4 f0 = *(const float4*)&SB[base];
    float4 f1 = *(const float4*)&SB[base + 4];
    float f[8] = {f0.x, f0.y, f0.z, f0.w, f1.x, f1.y, f1.z, f1.w};
#pragma unroll
    for (int e = 0; e < 8; ++e) {
      _Float16 h = (_Float16)f[e];
      ah[dc][e] = h;
      al[dc][e] = (_Float16)(f[e] - (float)h);
    }
  }
  __syncthreads();

  f32x4 acc[8];
#pragma unroll
  for (int a = 0; a < 8; ++a) acc[a] = (f32x4){0.f, 0.f, 0.f, 0.f};

#pragma unroll
  for (int dc = 0; dc < 4; ++dc) {
#pragma unroll
    for (int a = 0; a < 8; ++a) {
      const float* p = W + (size_t)(a * 16 + lr) * DD + dc * 32 + lg * 8;
      float4 f0 = *(const float4*)p;
      float4 f1 = *(const float4*)(p + 4);
      float f[8] = {f0.x, f0.y, f0.z, f0.w, f1.x, f1.y, f1.z, f1.w};
      half8 bh, bl;
#pragma unroll
      for (int e = 0; e < 8; ++e) {
        _Float16 h = (_Float16)f[e];
        bh[e] = h;
        bl[e] = (_Float16)(f[e] - (float)h);
      }
      acc[a] = mfma16(ah[dc], bh, acc[a]);
      acc[a] = mfma16(al[dc], bh, acc[a]);
      acc[a] = mfma16(ah[dc], bl, acc[a]);
    }
  }

  if (which < 2) {
    _Float16* Oh = (_Float16*)(wsb + (which == 0 ? QH_OFF : KH_OFF));
    _Float16* Ol = (_Float16*)(wsb + (which == 0 ? QL_OFF : KL_OFF));
#pragma unroll
    for (int a = 0; a < 8; ++a)
#pragma unroll
      for (int i = 0; i < 4; ++i) {
        const int ro = r0 + wv * 16 + lg * 4 + i;
        const int co = a * 16 + lr;
        float v = acc[a][i];
        _Float16 h = (_Float16)v;
        Oh[(size_t)ro * DD + co] = h;
        Ol[(size_t)ro * DD + co] = (_Float16)(v - (float)h);
      }
  } else {
    _Float16* TH = (_Float16*)SB;          // [128][68]
    _Float16* TL = TH + 8704;
#pragma unroll
    for (int a = 0; a < 8; ++a)
#pragma unroll
      for (int i = 0; i < 4; ++i) {
        const int rl = wv * 16 + lg * 4 + i;   // local k
        const int co = a * 16 + lr;            // d
        float v = acc[a][i];
        _Float16 h = (_Float16)v;
        TH[co * 68 + rl] = h;
        TL[co * 68 + rl] = (_Float16)(v - (float)h);
      }
    __syncthreads();
    _Float16* Vh = (_Float16*)(wsb + VTH_OFF);
    _Float16* Vl = (_Float16*)(wsb + VTL_OFF);
    const int b = r0 >> 11, kloc = r0 & 2047;
    const int d = t >> 1, hh = t & 1;
    const size_t gb = ((size_t)(b * DD + d)) * LK + kloc + hh * 32;
#pragma unroll
    for (int j = 0; j < 8; ++j) {
      *(ushort4*)(Vh + gb + j * 4) = *(const ushort4*)&TH[d * 68 + hh * 32 + j * 4];
      *(ushort4*)(Vl + gb + j * 4) = *(const ushort4*)&TL[d * 68 + hh * 32 + j * 4];
    }
  }
}

// ---------------- maskpack --------------------------------------------------
__global__ __launch_bounds__(256) void maskpack_kernel(
    const int* __restrict__ valid, unsigned long long* __restrict__ bm)
{
  const int t = threadIdx.x, l = t & 63, wv = t >> 6;
  const size_t base = (size_t)blockIdx.x * 32768 + (size_t)wv * 8192;
  for (int it = 0; it < 32; ++it) {
    int v0 = valid[base + (size_t)(it * 4 + 0) * 64 + l];
    int v1 = valid[base + (size_t)(it * 4 + 1) * 64 + l];
    int v2 = valid[base + (size_t)(it * 4 + 2) * 64 + l];
    int v3 = valid[base + (size_t)(it * 4 + 3) * 64 + l];
    unsigned long long m0 = __ballot(v0 > 0);
    unsigned long long m1 = __ballot(v1 > 0);
    unsigned long long m2 = __ballot(v2 > 0);
    unsigned long long m3 = __ballot(v3 > 0);
    if (l == 0) {
      bm[(base >> 6) + it * 4 + 0] = m0;
      bm[(base >> 6) + it * 4 + 1] = m1;
      bm[(base >> 6) + it * 4 + 2] = m2;
      bm[(base >> 6) + it * 4 + 3] = m3;
    }
  }
}

// ---------------- scores ----------------------------------------------------
// grid (LQ/64, B, KS). Block: 4 waves x 16 q-rows, k-range 512 (8 tiles of 64).
// K LDS [64][128] f16 (hi & lo), XOR-swizzled on 8-half granules, no padding.
__global__ __launch_bounds__(256, 4) void scores_kernel(
    const unsigned char* __restrict__ wsb, float* __restrict__ att)
{
  __shared__ _Float16 KHs[64 * 128];
  __shared__ _Float16 KLs[64 * 128];
  const int t = threadIdx.x, l = t & 63, wv = t >> 6;
  const int lr = l & 15, lg = l >> 4;
  const int qb = blockIdx.x, b = blockIdx.y, ks = blockIdx.z;
  const int rowg = b * LQ + qb * 64;
  const int kbase = ks * 512;
  const _Float16* QH = (const _Float16*)(wsb + QH_OFF);
  const _Float16* QL = (const _Float16*)(wsb + QL_OFF);
  const _Float16* KH = (const _Float16*)(wsb + KH_OFF);
  const _Float16* KL = (const _Float16*)(wsb + KL_OFF);
  const unsigned* bm32 = (const unsigned*)(wsb + BM_OFF);
  float* M = (float*)(wsb + MZ_OFF);
  float* Z = M + KS * NROWS;

  half8 qh[4], ql[4];
#pragma unroll
  for (int dc = 0; dc < 4; ++dc) {
    const size_t idx = ((size_t)(rowg + wv * 16 + lr)) * DD + dc * 32 + lg * 8;
    qh[dc] = *(const half8*)(QH + idx);
    ql[dc] = *(const half8*)(QL + idx);
  }

  half8 rh[4], rl[4];
  auto issue_stage = [&](int kt) {
#pragma unroll
    for (int j = 0; j < 4; ++j) {
      const int flat = j * 2048 + t * 8;
      const int row = flat >> 7, col = flat & 127;
      const size_t g = ((size_t)(b * LK + kbase + kt * 64 + row)) * DD + col;
      rh[j] = *(const half8*)(KH + g);
      rl[j] = *(const half8*)(KL + g);
    }
  };
  auto write_stage = [&]() {
#pragma unroll
    for (int j = 0; j < 4; ++j) {
      const int flat = j * 2048 + t * 8;
      const int row = flat >> 7, c8 = (flat >> 3) & 15;
      const int c8s = (c8 & 8) | ((c8 ^ row) & 7);
      *(half8*)&KHs[row * 128 + c8s * 8] = rh[j];
      *(half8*)&KLs[row * 128 + c8s * 8] = rl[j];
    }
  };

  issue_stage(0);
  write_stage();

  float m_run[4], z_run[4];
#pragma unroll
  for (int i = 0; i < 4; ++i) { m_run[i] = -FLT_MAX; z_run[i] = 0.f; }

  for (int kt = 0; kt < 8; ++kt) {
    const int k0 = kbase + kt * 64;
    if (kt < 7) issue_stage(kt + 1);
    unsigned mw0[4], mw1[4];
#pragma unroll
    for (int i = 0; i < 4; ++i) {
      uint2 u = *(const uint2*)(bm32 + ((size_t)(rowg + wv * 16 + lg * 4 + i)) * 64 + (k0 >> 5));
      mw0[i] = u.x; mw1[i] = u.y;
    }
    __syncthreads();   // tile kt staged

    f32x4 acc[4];
#pragma unroll
    for (int kg = 0; kg < 4; ++kg) acc[kg] = (f32x4){0.f, 0.f, 0.f, 0.f};
#pragma unroll
    for (int kg = 0; kg < 4; ++kg)
#pragma unroll
      for (int dc = 0; dc < 4; ++dc) {
        const int c8 = dc * 4 + lg;
        const int c8s = (c8 & 8) | ((c8 ^ lr) & 7);   // row&7 == lr&7
        half8 bh = *(const half8*)&KHs[(kg * 16 + lr) * 128 + c8s * 8];
        half8 bl = *(const half8*)&KLs[(kg * 16 + lr) * 128 + c8s * 8];
        acc[kg] = mfma16(qh[dc], bh, acc[kg]);
        acc[kg] = mfma16(ql[dc], bh, acc[kg]);
        acc[kg] = mfma16(qh[dc], bl, acc[kg]);
      }

#pragma unroll
    for (int i = 0; i < 4; ++i) {
      float sv[4];
      float* ap = att + ((size_t)(rowg + wv * 16 + lg * 4 + i)) * LK + k0 + lr;
#pragma unroll
      for (int kg = 0; kg < 4; ++kg) {
        unsigned w = (kg < 2) ? mw0[i] : mw1[i];
        int bit = (w >> (((kg & 1) * 16) + lr)) & 1;
        float v = bit ? acc[kg][i] : -INFINITY;
        sv[kg] = v;
        ap[kg * 16] = v;
      }
      float tm = fmaxf(fmaxf(sv[0], sv[1]), fmaxf(sv[2], sv[3]));
#pragma unroll
      for (int o = 1; o < 16; o <<= 1) tm = fmaxf(tm, __shfl_xor(tm, o));
      const float mo = m_run[i], mn = fmaxf(mo, tm);
      float za = __expf(sv[0] - mn) + __expf(sv[1] - mn) +
                 __expf(sv[2] - mn) + __expf(sv[3] - mn);
      z_run[i] = z_run[i] * __expf(mo - mn) + za;
      m_run[i] = mn;
    }
    __syncthreads();   // LDS reads done
    if (kt < 7) write_stage();
  }

#pragma unroll
  for (int i = 0; i < 4; ++i) {
    float z = z_run[i];
#pragma unroll
    for (int o = 1; o < 16; o <<= 1) z += __shfl_xor(z, o);
    if (lr == 0) {
      const size_t row = (size_t)(rowg + wv * 16 + lg * 4 + i);
      M[(size_t)ks * NROWS + row] = m_run[i];
      Z[(size_t)ks * NROWS + row] = z;
    }
  }
}

// ---------------- pv --------------------------------------------------------
// grid (LQ/64, B, KS). Block: 4 waves x 16 q-rows, k-range 512 (8 tiles of 64).
// LDS: V [128][64] f16 swizzled (16 KB) + w [64][64] f16 swizzled (8 KB).
__global__ __launch_bounds__(256, 4) void pv_kernel(
    const unsigned char* __restrict__ wsb, float* __restrict__ att,
    float* __restrict__ res)
{
  __shared__ _Float16 VHs[128 * 64];
  __shared__ _Float16 Wt[64 * 64];
  const int t = threadIdx.x, l = t & 63, wv = t >> 6;
  const int lr = l & 15, lg = l >> 4;
  const int qb = blockIdx.x, b = blockIdx.y, kp = blockIdx.z;
  const int rowg = b * LQ + qb * 64;
  const int kbase = kp * 512;
  const _Float16* VTH = (const _Float16*)(wsb + VTH_OFF);
  const float* M = (const float*)(wsb + MZ_OFF);
  const float* Z = M + KS * NROWS;

  // per-thread staging row & global m,zi for it
  const int srow = t >> 2, scb = (t & 3) * 16;
  float mg, zi;
  {
    const size_t row = (size_t)(rowg + srow);
    float m0 = M[row], m1 = M[NROWS + row], m2 = M[2 * NROWS + row], m3 = M[3 * NROWS + row];
    mg = fmaxf(fmaxf(m0, m1), fmaxf(m2, m3));
    float z = Z[row] * __expf(m0 - mg) + Z[NROWS + row] * __expf(m1 - mg) +
              Z[2 * NROWS + row] * __expf(m2 - mg) + Z[3 * NROWS + row] * __expf(m3 - mg);
    zi = (z > 0.f) ? 1.f / z : 0.f;
  }

  half8 vhr[4];
  float4 sr[4];
  auto issue_V = [&](int kt) {
#pragma unroll
    for (int j = 0; j < 4; ++j) {
      const int flat = j * 2048 + t * 8;
      const int d = flat >> 6, kk = flat & 63;
      vhr[j] = *(const half8*)(VTH + ((size_t)(b * DD + d)) * LK + kbase + kt * 64 + kk);
    }
  };
  auto issue_S = [&](int kt) {
    const size_t rb = (size_t)(rowg + srow) * LK + kbase + kt * 64 + scb;
#pragma unroll
    for (int j = 0; j < 4; ++j) sr[j] = *(const float4*)&att[rb + j * 4];
  };
  // compute w from sr, write att_w + swizzled LDS w-tile; commit V regs to LDS
  auto w_stage = [&](int kt) {
    const size_t rb = (size_t)(rowg + srow) * LK + kbase + kt * 64 + scb;
    float wf[16];
#pragma unroll
    for (int j = 0; j < 4; ++j) {
      float4 w4;
      w4.x = __expf(sr[j].x - mg) * zi;
      w4.y = __expf(sr[j].y - mg) * zi;
      w4.z = __expf(sr[j].z - mg) * zi;
      w4.w = __expf(sr[j].w - mg) * zi;
      *(float4*)&att[rb + j * 4] = w4;
      wf[j * 4 + 0] = w4.x; wf[j * 4 + 1] = w4.y;
      wf[j * 4 + 2] = w4.z; wf[j * 4 + 3] = w4.w;
    }
    half8 h0, h1;
#pragma unroll
    for (int e = 0; e < 8; ++e) { h0[e] = (_Float16)wf[e]; h1[e] = (_Float16)wf[8 + e]; }
    const int g0 = (t & 3) * 2;
    *(half8*)&Wt[srow * 64 + (((g0)     ^ srow) & 7) * 8] = h0;
    *(half8*)&Wt[srow * 64 + (((g0 + 1) ^ srow) & 7) * 8] = h1;
#pragma unroll
    for (int j = 0; j < 4; ++j) {
      const int flat = j * 2048 + t * 8;
      const int d = flat >> 6, c8 = (flat >> 3) & 7;
      *(half8*)&VHs[d * 64 + ((c8 ^ d) & 7) * 8] = vhr[j];
    }
  };

  f32x4 oacc[8];
#pragma unroll
  for (int df = 0; df < 8; ++df) oacc[df] = (f32x4){0.f, 0.f, 0.f, 0.f};

  issue_V(0); issue_S(0);
  w_stage(0);
  __syncthreads();

  for (int kt = 0; kt < 8; ++kt) {
    if (kt < 7) { issue_V(kt + 1); issue_S(kt + 1); }

#pragma unroll
    for (int kc = 0; kc < 2; ++kc) {
      const int c8 = kc * 4 + lg;
      half8 wfr = *(const half8*)&Wt[(wv * 16 + lr) * 64 + ((c8 ^ (lr & 7)) & 7) * 8];
#pragma unroll
      for (int df = 0; df < 8; ++df) {
        half8 vh = *(const half8*)&VHs[(df * 16 + lr) * 64 + ((c8 ^ (lr & 7)) & 7) * 8];
        oacc[df] = mfma16(wfr, vh, oacc[df]);
      }
    }
    __syncthreads();   // LDS reads done
    if (kt < 7) {
      w_stage(kt + 1);
      __syncthreads();
    }
  }

#pragma unroll
  for (int df = 0; df < 8; ++df)
#pragma unroll
    for (int i = 0; i < 4; ++i)
      atomicAdd(&res[((size_t)(rowg + wv * 16 + lg * 4 + i)) * DD + df * 16 + lr],
                oacc[df][i]);
}

extern "C" void kernel_launch(void* const* d_in, const int* in_sizes, int n_in,
                              void* d_out, int out_size, void* d_ws, size_t ws_size,
                              hipStream_t stream)
{
  (void)in_sizes; (void)n_in; (void)out_size; (void)ws_size;
  const float* query = (const float*)d_in[0];
  const float* x     = (const float*)d_in[1];
  const int*   valid = (const int*)d_in[2];
  const float* Wq    = (const float*)d_in[3];
  const float* Wk    = (const float*)d_in[4];
  const float* Wv    = (const float*)d_in[5];

  float* out = (float*)d_out;
  float* res = out;                          // [B][LQ][D]
  float* att = out + (size_t)NROWS * DD;     // [B][LQ][LK]
  unsigned char* wsb = (unsigned char*)d_ws; // ~30 MB used

  hipMemsetAsync(res, 0, (size_t)NROWS * DD * sizeof(float), stream);
  proj_kernel<<<dim3(NROWS / 64, 3), 256, 0, stream>>>(query, x, Wq, Wk, Wv, wsb);
  maskpack_kernel<<<dim3(1024), 256, 0, stream>>>(
      valid, (unsigned long long*)(wsb + BM_OFF));
  scores_kernel<<<dim3(LQ / 64, BB, KS), 256, 0, stream>>>(wsb, att);
  pv_kernel<<<dim3(LQ / 64, BB, KS), 256, 0, stream>>>(wsb, att, res);
}

// Round 8
// 365.517 us; speedup vs baseline: 1.8596x; 1.1402x over previous
//
#include <hip/hip_runtime.h>
#include <float.h>
#include <math.h>

// CrossAtt, f16 split MFMA, fused 2-pass flash attention (no S round-trip).
// proj    : Qh/Ql (f16 hi/lo), Kh (f16 hi only), Vt (transposed f16 hi) in ws.
// maskpack: valid int32 -> bitmask, 4 MB.
// fused   : per block (32 q-rows, full K): pass1 QK^T (2-term, K in swizzled
//           LDS) -> m,z ; pair-merge; pass2 bit-identical QK^T -> w =
//           exp(S-m)*zi -> att_w direct + LDS w-tile -> PV (w x Vt, swizzled
//           LDS) -> cross-pair O reduce -> res. XCD-pinned batch (b = blk&7).

#define BB 8
#define LQ 2048
#define LK 2048
#define DD 128
#define NROWS (BB*LQ)
#define QB 32

typedef __attribute__((ext_vector_type(8))) _Float16 half8;
typedef __attribute__((ext_vector_type(4))) float f32x4;

// ws byte offsets (20 MB total)
#define QH_OFF  (0u)
#define QL_OFF  (4194304u)
#define KH_OFF  (8388608u)
#define VTH_OFF (12582912u)
#define BM_OFF  (16777216u)

__device__ __forceinline__ f32x4 mfma16(half8 a, half8 b, f32x4 c) {
  return __builtin_amdgcn_mfma_f32_16x16x32_f16(a, b, c, 0, 0, 0);
}

// ---------------- proj ------------------------------------------------------
__global__ __launch_bounds__(256, 3) void proj_kernel(
    const float* __restrict__ query, const float* __restrict__ x,
    const float* __restrict__ Wq, const float* __restrict__ Wk,
    const float* __restrict__ Wv, unsigned char* __restrict__ wsb)
{
  __shared__ float SB[8704];   // src tile [64][132]; reused as TH f16 [128][68]
  const int which = blockIdx.y;
  const float* __restrict__ src = (which == 0) ? query : x;
  const float* __restrict__ W   = (which == 0) ? Wq : (which == 1 ? Wk : Wv);
  const int t = threadIdx.x, l = t & 63, wv = t >> 6;
  const int lr = l & 15, lg = l >> 4;
  const int r0 = blockIdx.x * 64;

#pragma unroll
  for (int j = 0; j < 8; ++j) {
    const int flat = j * 1024 + t * 4;
    const int row = flat >> 7, col = flat & 127;
    *(float4*)&SB[row * 132 + col] = *(const float4*)&src[(size_t)(r0 + row) * DD + col];
  }
  __syncthreads();

  half8 ah[4], al[4];
#pragma unroll
  for (int dc = 0; dc < 4; ++dc) {
    const int base = (wv * 16 + lr) * 132 + dc * 32 + lg * 8;
    float4 f0 = *(const float4*)&SB[base];
    float4 f1 = *(const float4*)&SB[base + 4];
    float f[8] = {f0.x, f0.y, f0.z, f0.w, f1.x, f1.y, f1.z, f1.w};
#pragma unroll
    for (int e = 0; e < 8; ++e) {
      _Float16 h = (_Float16)f[e];
      ah[dc][e] = h;
      al[dc][e] = (_Float16)(f[e] - (float)h);
    }
  }
  __syncthreads();

  f32x4 acc[8];
#pragma unroll
  for (int a = 0; a < 8; ++a) acc[a] = (f32x4){0.f, 0.f, 0.f, 0.f};

#pragma unroll
  for (int dc = 0; dc < 4; ++dc) {
#pragma unroll
    for (int a = 0; a < 8; ++a) {
      const float* p = W + (size_t)(a * 16 + lr) * DD + dc * 32 + lg * 8;
      float4 f0 = *(const float4*)p;
      float4 f1 = *(const float4*)(p + 4);
      float f[8] = {f0.x, f0.y, f0.z, f0.w, f1.x, f1.y, f1.z, f1.w};
      half8 bh, bl;
#pragma unroll
      for (int e = 0; e < 8; ++e) {
        _Float16 h = (_Float16)f[e];
        bh[e] = h;
        bl[e] = (_Float16)(f[e] - (float)h);
      }
      acc[a] = mfma16(ah[dc], bh, acc[a]);
      acc[a] = mfma16(al[dc], bh, acc[a]);
      acc[a] = mfma16(ah[dc], bl, acc[a]);
    }
  }

  if (which == 0) {
    _Float16* Oh = (_Float16*)(wsb + QH_OFF);
    _Float16* Ol = (_Float16*)(wsb + QL_OFF);
#pragma unroll
    for (int a = 0; a < 8; ++a)
#pragma unroll
      for (int i = 0; i < 4; ++i) {
        const int ro = r0 + wv * 16 + lg * 4 + i;
        const int co = a * 16 + lr;
        float v = acc[a][i];
        _Float16 h = (_Float16)v;
        Oh[(size_t)ro * DD + co] = h;
        Ol[(size_t)ro * DD + co] = (_Float16)(v - (float)h);
      }
  } else if (which == 1) {
    _Float16* Oh = (_Float16*)(wsb + KH_OFF);
#pragma unroll
    for (int a = 0; a < 8; ++a)
#pragma unroll
      for (int i = 0; i < 4; ++i) {
        const int ro = r0 + wv * 16 + lg * 4 + i;
        const int co = a * 16 + lr;
        Oh[(size_t)ro * DD + co] = (_Float16)acc[a][i];
      }
  } else {
    _Float16* TH = (_Float16*)SB;          // [128][68]
#pragma unroll
    for (int a = 0; a < 8; ++a)
#pragma unroll
      for (int i = 0; i < 4; ++i) {
        const int rl = wv * 16 + lg * 4 + i;   // local k
        const int co = a * 16 + lr;            // d
        TH[co * 68 + rl] = (_Float16)acc[a][i];
      }
    __syncthreads();
    _Float16* Vh = (_Float16*)(wsb + VTH_OFF);
    const int b = r0 >> 11, kloc = r0 & 2047;
    const int d = t >> 1, hh = t & 1;
    const size_t gb = ((size_t)(b * DD + d)) * LK + kloc + hh * 32;
#pragma unroll
    for (int j = 0; j < 8; ++j)
      *(ushort4*)(Vh + gb + j * 4) = *(const ushort4*)&TH[d * 68 + hh * 32 + j * 4];
  }
}

// ---------------- maskpack --------------------------------------------------
__global__ __launch_bounds__(256) void maskpack_kernel(
    const int* __restrict__ valid, unsigned long long* __restrict__ bm)
{
  const int t = threadIdx.x, l = t & 63, wv = t >> 6;
  const size_t base = (size_t)blockIdx.x * 32768 + (size_t)wv * 8192;
  for (int it = 0; it < 32; ++it) {
    int v0 = valid[base + (size_t)(it * 4 + 0) * 64 + l];
    int v1 = valid[base + (size_t)(it * 4 + 1) * 64 + l];
    int v2 = valid[base + (size_t)(it * 4 + 2) * 64 + l];
    int v3 = valid[base + (size_t)(it * 4 + 3) * 64 + l];
    unsigned long long m0 = __ballot(v0 > 0);
    unsigned long long m1 = __ballot(v1 > 0);
    unsigned long long m2 = __ballot(v2 > 0);
    unsigned long long m3 = __ballot(v3 > 0);
    if (l == 0) {
      bm[(base >> 6) + it * 4 + 0] = m0;
      bm[(base >> 6) + it * 4 + 1] = m1;
      bm[(base >> 6) + it * 4 + 2] = m2;
      bm[(base >> 6) + it * 4 + 3] = m3;
    }
  }
}

// ---------------- fused attention -------------------------------------------
// grid 512 linear: b = blk&7 (XCD-pinned batch), qb = blk>>3 (32 q-rows).
// Waves: rg = wv>>1 (16-row group), kh = wv&1 (32-col half of each 64-k tile).
__global__ __launch_bounds__(256, 2) void fused_kernel(
    const unsigned char* __restrict__ wsb,
    float* __restrict__ att, float* __restrict__ res)
{
  __shared__ __align__(16) unsigned char SM[37376];
  _Float16* KHs = (_Float16*)SM;              // [64][128] f16 swizzled, 16 KB
  _Float16* Vs  = (_Float16*)(SM + 16384);    // [128][64] f16 swizzled, 16 KB
  _Float16* Wt  = (_Float16*)(SM + 32768);    // [32][64]  f16 swizzled, 4 KB
  float*    MZ  = (float*)(SM + 36864);       // [4][16][2]
  float*    Osum = (float*)SM;                // [32][132] f32 overlay (post-loop)

  const int t = threadIdx.x, l = t & 63, wv = t >> 6;
  const int lr = l & 15, lg = l >> 4;
  const int rg = wv >> 1, kh = wv & 1;
  const int lin = blockIdx.x;
  const int b = lin & 7, qb = lin >> 3;
  const int rowg = b * LQ + qb * QB;

  const _Float16* QH = (const _Float16*)(wsb + QH_OFF);
  const _Float16* QL = (const _Float16*)(wsb + QL_OFF);
  const _Float16* KH = (const _Float16*)(wsb + KH_OFF);
  const _Float16* VT = (const _Float16*)(wsb + VTH_OFF);
  const unsigned* bm32 = (const unsigned*)(wsb + BM_OFF);

  // Q fragments (whole-kernel lifetime)
  half8 qh[4], ql[4];
#pragma unroll
  for (int dc = 0; dc < 4; ++dc) {
    const size_t idx = ((size_t)(rowg + rg * 16 + lr)) * DD + dc * 32 + lg * 8;
    qh[dc] = *(const half8*)(QH + idx);
    ql[dc] = *(const half8*)(QL + idx);
  }

  half8 rk[4], rv[4];
  auto issueK = [&](int kt) {
#pragma unroll
    for (int j = 0; j < 4; ++j) {
      const int flat = j * 2048 + t * 8;
      const int row = flat >> 7, col = flat & 127;
      rk[j] = *(const half8*)(KH + ((size_t)(b * LK + kt * 64 + row)) * DD + col);
    }
  };
  auto writeK = [&]() {
#pragma unroll
    for (int j = 0; j < 4; ++j) {
      const int flat = j * 2048 + t * 8;
      const int row = flat >> 7, c8 = (flat >> 3) & 15;
      const int c8s = (c8 & 8) | ((c8 ^ row) & 7);
      *(half8*)&KHs[row * 128 + c8s * 8] = rk[j];
    }
  };
  auto issueV = [&](int kt) {
#pragma unroll
    for (int j = 0; j < 4; ++j) {
      const int flat = j * 2048 + t * 8;
      const int d = flat >> 6, kk = flat & 63;
      rv[j] = *(const half8*)(VT + ((size_t)(b * DD + d)) * LK + kt * 64 + kk);
    }
  };
  auto writeV = [&]() {
#pragma unroll
    for (int j = 0; j < 4; ++j) {
      const int flat = j * 2048 + t * 8;
      const int d = flat >> 6, c8 = (flat >> 3) & 7;
      *(half8*)&Vs[d * 64 + ((c8 ^ d) & 7) * 8] = rv[j];
    }
  };
  // 2-term S = (qh+ql) x Kh; SAME code both passes -> bit-identical S.
  auto computeQK = [&](f32x4* acc) {
    acc[0] = (f32x4){0.f, 0.f, 0.f, 0.f};
    acc[1] = (f32x4){0.f, 0.f, 0.f, 0.f};
#pragma unroll
    for (int g = 0; g < 2; ++g)
#pragma unroll
      for (int dc = 0; dc < 4; ++dc) {
        const int c8 = dc * 4 + lg;
        const int c8s = (c8 & 8) | ((c8 ^ lr) & 7);
        half8 bh = *(const half8*)&KHs[((2 * kh + g) * 16 + lr) * 128 + c8s * 8];
        acc[g] = mfma16(ql[dc], bh, acc[g]);
        acc[g] = mfma16(qh[dc], bh, acc[g]);
      }
  };

  // ---- pass 1: m,z over this wave's k-half ----
  float m_run[4], z_run[4];
#pragma unroll
  for (int i = 0; i < 4; ++i) { m_run[i] = -FLT_MAX; z_run[i] = 0.f; }

  issueK(0); writeK();
  for (int kt = 0; kt < 32; ++kt) {
    if (kt < 31) issueK(kt + 1);
    unsigned mw[4];
#pragma unroll
    for (int i = 0; i < 4; ++i)
      mw[i] = bm32[((size_t)(rowg + rg * 16 + lg * 4 + i)) * 64 + kt * 2 + kh];
    __syncthreads();   // tile kt staged
    f32x4 acc[2];
    computeQK(acc);
#pragma unroll
    for (int i = 0; i < 4; ++i) {
      float sv0 = ((mw[i] >> lr) & 1) ? acc[0][i] : -INFINITY;
      float sv1 = ((mw[i] >> (16 + lr)) & 1) ? acc[1][i] : -INFINITY;
      float tm = fmaxf(sv0, sv1);
#pragma unroll
      for (int o = 1; o < 16; o <<= 1) tm = fmaxf(tm, __shfl_xor(tm, o));
      const float mo = m_run[i], mn = fmaxf(mo, tm);
      z_run[i] = z_run[i] * __expf(mo - mn) + __expf(sv0 - mn) + __expf(sv1 - mn);
      m_run[i] = mn;
    }
    __syncthreads();   // LDS reads done
    if (kt < 31) writeK();
  }

  // ---- merge m,z across the wave pair (kh=0/1 share rows) ----
#pragma unroll
  for (int i = 0; i < 4; ++i) {
    float z = z_run[i];
#pragma unroll
    for (int o = 1; o < 16; o <<= 1) z += __shfl_xor(z, o);
    if (lr == 0) {
      MZ[(wv * 16 + lg * 4 + i) * 2]     = m_run[i];
      MZ[(wv * 16 + lg * 4 + i) * 2 + 1] = z;
    }
  }
  __syncthreads();
  float mf[4], zif[4];
#pragma unroll
  for (int i = 0; i < 4; ++i) {
    const int r = lg * 4 + i, pw = wv ^ 1;
    float m1 = MZ[(wv * 16 + r) * 2], z1 = MZ[(wv * 16 + r) * 2 + 1];
    float m2 = MZ[(pw * 16 + r) * 2], z2 = MZ[(pw * 16 + r) * 2 + 1];
    float m = fmaxf(m1, m2);
    float z = z1 * __expf(m1 - m) + z2 * __expf(m2 - m);
    mf[i] = m;
    zif[i] = (z > 0.f) ? 1.f / z : 0.f;
  }

  // ---- pass 2: recompute S, write att_w, PV ----
  f32x4 oacc[8];
#pragma unroll
  for (int df = 0; df < 8; ++df) oacc[df] = (f32x4){0.f, 0.f, 0.f, 0.f};

  issueK(0); issueV(0);
  writeK(); writeV();
  for (int kt = 0; kt < 32; ++kt) {
    if (kt < 31) { issueK(kt + 1); issueV(kt + 1); }
    unsigned mw[4];
#pragma unroll
    for (int i = 0; i < 4; ++i)
      mw[i] = bm32[((size_t)(rowg + rg * 16 + lg * 4 + i)) * 64 + kt * 2 + kh];
    __syncthreads();   // tiles kt staged
    f32x4 acc[2];
    computeQK(acc);
#pragma unroll
    for (int i = 0; i < 4; ++i) {
      const int rloc = rg * 16 + lg * 4 + i;
      float* ap = att + ((size_t)(rowg + rloc)) * LK + kt * 64 + kh * 32 + lr;
#pragma unroll
      for (int g = 0; g < 2; ++g) {
        const int bit = (mw[i] >> (g * 16 + lr)) & 1;
        float sm_ = bit ? acc[g][i] : -INFINITY;
        float w = __expf(sm_ - mf[i]) * zif[i];
        ap[g * 16] = w;
        const int c = kh * 32 + g * 16 + lr;
        Wt[rloc * 64 + (((c >> 3) ^ (rloc & 7)) & 7) * 8 + (c & 7)] = (_Float16)w;
      }
    }
    // same-wave LDS write->read: HW DS ops are in-order per wave; fence stops
    // compiler reordering only.
    asm volatile("" ::: "memory");
    {
      const int c8s = ((kh * 4 + lg) ^ (lr & 7)) & 7;
      half8 pa = *(const half8*)&Wt[(rg * 16 + lr) * 64 + c8s * 8];
#pragma unroll
      for (int df = 0; df < 8; ++df) {
        half8 vb = *(const half8*)&Vs[(df * 16 + lr) * 64 + c8s * 8];
        oacc[df] = mfma16(pa, vb, oacc[df]);
      }
    }
    __syncthreads();   // LDS reads done
    if (kt < 31) { writeK(); writeV(); }
  }

  // ---- cross-pair O reduce (Osum overlays staging LDS) + coalesced store ----
  if (kh == 1) {
#pragma unroll
    for (int df = 0; df < 8; ++df)
#pragma unroll
      for (int i = 0; i < 4; ++i)
        Osum[(rg * 16 + lg * 4 + i) * 132 + df * 16 + lr] = oacc[df][i];
  }
  __syncthreads();
  if (kh == 0) {
#pragma unroll
    for (int df = 0; df < 8; ++df)
#pragma unroll
      for (int i = 0; i < 4; ++i) {
        const int idx = (rg * 16 + lg * 4 + i) * 132 + df * 16 + lr;
        Osum[idx] += oacc[df][i];
      }
  }
  __syncthreads();
#pragma unroll
  for (int j = 0; j < 4; ++j) {
    const int flat = j * 1024 + t * 4;
    const int r = flat >> 7, d = flat & 127;
    *(float4*)&res[((size_t)(rowg + r)) * DD + d] = *(const float4*)&Osum[r * 132 + d];
  }
}

extern "C" void kernel_launch(void* const* d_in, const int* in_sizes, int n_in,
                              void* d_out, int out_size, void* d_ws, size_t ws_size,
                              hipStream_t stream)
{
  (void)in_sizes; (void)n_in; (void)out_size; (void)ws_size;
  const float* query = (const float*)d_in[0];
  const float* x     = (const float*)d_in[1];
  const int*   valid = (const int*)d_in[2];
  const float* Wq    = (const float*)d_in[3];
  const float* Wk    = (const float*)d_in[4];
  const float* Wv    = (const float*)d_in[5];

  float* out = (float*)d_out;
  float* res = out;                          // [B][LQ][D]
  float* att = out + (size_t)NROWS * DD;     // [B][LQ][LK]
  unsigned char* wsb = (unsigned char*)d_ws; // 20 MB used

  proj_kernel<<<dim3(NROWS / 64, 3), 256, 0, stream>>>(query, x, Wq, Wk, Wv, wsb);
  maskpack_kernel<<<dim3(1024), 256, 0, stream>>>(
      valid, (unsigned long long*)(wsb + BM_OFF));
  fused_kernel<<<dim3(512), 256, 0, stream>>>(wsb, att, res);
}